// Round 6
// baseline (151.141 us; speedup 1.0000x reference)
//
#include <hip/hip_runtime.h>

typedef __bf16 v8bf __attribute__((ext_vector_type(8)));
typedef float  v4f  __attribute__((ext_vector_type(4)));

#define D     512
#define NSUP  20
#define NC    64
#define RES   25
#define BB    128
#define LAM   (20.0f/512.0f)
#define KT    32
#define NKT   (D/KT)     // 16
#define CPB   8
#define COLS  160        // CPB*NSUP
#define NFRAG 10         // COLS/16
#define MFRAG 4          // 64 rows / 16

__device__ __forceinline__ ushort bf_hi(float v) {
    uint32_t b = __float_as_uint(v);
    return (ushort)((b + 0x7FFF + ((b >> 16) & 1)) >> 16);   // RNE
}
__device__ __forceinline__ float us2f(ushort u) {
    return __uint_as_float(((uint32_t)u) << 16);
}

// ---- Kernel 1: A=inv(G+lam I); M=A+lam*A^2 (SPD); M=LL^T; Htilde=L^T H ----
// Small-matrix chain runs on wave 0 ONLY, barrier-free (fences instead of
// __syncthreads): 3 block barriers total vs ~150 before.
__global__ __launch_bounds__(256) void k_prep(const float* __restrict__ high,
                                              ushort* __restrict__ Hth,
                                              ushort* __restrict__ Htl) {
    const int cls = blockIdx.x;
    const int t   = threadIdx.x;
    __shared__ float Hc[NSUP * 516];
    __shared__ float Gs[NSUP * NSUP];
    __shared__ float Aug[NSUP * 41];
    __shared__ float Ms[NSUP * NSUP];
    __shared__ float fcol[NSUP];

    // stage class rows (float4)
    for (int i = t; i < NSUP * (D / 4); i += 256) {
        int r = i >> 7, c4 = (i & 127) << 2;
        *(float4*)&Hc[r * 516 + c4] = *(const float4*)&high[(cls * NSUP + r) * D + c4];
    }
    __syncthreads();                                    // barrier 1

    // Gram — symmetric half only (210 dot products instead of 400)
    for (int e = t; e < NSUP * NSUP; e += 256) {
        int i = e / NSUP, j = e % NSUP;
        if (i <= j) {
            float s = 0.f;
            for (int k = 0; k < D; k += 4) {
                float4 a = *(float4*)&Hc[i * 516 + k];
                float4 b = *(float4*)&Hc[j * 516 + k];
                s += a.x * b.x + a.y * b.y + a.z * b.z + a.w * b.w;
            }
            Gs[i * NSUP + j] = s;
            Gs[j * NSUP + i] = s;
        }
    }
    __syncthreads();                                    // barrier 2

    if (t < 64) {   // ---------------- wave 0 only, no block barriers --------
        // Aug = [G + lam I | I]
        for (int e = t; e < NSUP * 41; e += 64) {
            int r = e / 41, c = e % 41;
            float v = 0.f;
            if (c < NSUP)      v = Gs[r * NSUP + c] + (c == r ? LAM : 0.f);
            else if (c < 40)   v = ((c - NSUP) == r) ? 1.f : 0.f;
            Aug[e] = v;
        }
        __threadfence_block();

        // Gauss-Jordan (SPD -> no pivoting)
        for (int k = 0; k < NSUP; ++k) {
            float ip = 1.f / Aug[k * 41 + k];           // broadcast read
            if (t < NSUP) fcol[t] = Aug[t * 41 + k];    // pre-scale col snapshot
            __threadfence_block();
            if (t < 40) Aug[k * 41 + t] *= ip;          // scale pivot row
            __threadfence_block();
            for (int e = t; e < 800; e += 64) {         // eliminate
                int r = e / 40, c = e % 40;
                if (r != k) Aug[r * 41 + c] -= fcol[r] * Aug[k * 41 + c];
            }
            __threadfence_block();
        }

        // M = A + lam*A^2   (A = Aug[:,20:40])
        for (int e = t; e < NSUP * NSUP; e += 64) {
            int i = e / NSUP, j = e % NSUP;
            float s = 0.f;
            for (int m = 0; m < NSUP; ++m) s += Aug[i * 41 + 20 + m] * Aug[m * 41 + 20 + j];
            Ms[e] = Aug[i * 41 + 20 + j] + LAM * s;
        }
        __threadfence_block();

        // Cholesky (lower): M = L L^T
        for (int k = 0; k < NSUP; ++k) {
            float piv = Ms[k * NSUP + k];               // all lanes read first
            float sq  = sqrtf(piv);
            if (t == k) Ms[k * NSUP + k] = sq;
            if (t > k && t < NSUP) Ms[t * NSUP + k] /= sq;
            __threadfence_block();
            for (int e = t; e < NSUP * NSUP; e += 64) {
                int i = e / NSUP, j = e % NSUP;
                if (j > k && j <= i) Ms[i * NSUP + j] -= Ms[i * NSUP + k] * Ms[j * NSUP + k];
            }
            __threadfence_block();
        }
    }
    __syncthreads();                                    // barrier 3

    // Htilde[i][k] = sum_{m>=i} L[m][i]*Hc[m][k] — column-per-thread,
    // Ms reads are wave-uniform broadcasts; exact hi/lo bf16 split.
    float h0[NSUP], h1[NSUP];
    #pragma unroll
    for (int m = 0; m < NSUP; ++m) {
        h0[m] = Hc[m * 516 + t];
        h1[m] = Hc[m * 516 + t + 256];
    }
    #pragma unroll
    for (int i = 0; i < NSUP; ++i) {
        float s0 = 0.f, s1 = 0.f;
        #pragma unroll
        for (int m = i; m < NSUP; ++m) {
            float lmi = Ms[m * NSUP + i];
            s0 += lmi * h0[m];
            s1 += lmi * h1[m];
        }
        ushort hh; float rr;
        hh = bf_hi(s0); rr = s0 - us2f(hh);
        Hth[(cls * NSUP + i) * D + t] = hh;
        Htl[(cls * NSUP + i) * D + t] = bf_hi(rr);
        hh = bf_hi(s1); rr = s1 - us2f(hh);
        Hth[(cls * NSUP + i) * D + t + 256] = hh;
        Htl[(cls * NSUP + i) * D + t + 256] = bf_hi(rr);
    }
}

// ---- Kernel 2: Z = X @ Htilde^T via 4-pass hi/lo bf16 MFMA; S = sum z^2 ----
// grid (8 class-groups, 64 batch-pairs), 256 threads = 4 waves (2M x 2N)
__global__ __launch_bounds__(256, 2) void k_main(const float* __restrict__ x,
                                                 const ushort* __restrict__ Hth,
                                                 const ushort* __restrict__ Htl,
                                                 float* __restrict__ S) {
    const int cg = blockIdx.x, bp = blockIdx.y;
    const int t = threadIdx.x, lane = t & 63, wid = t >> 6;
    const int wm = wid >> 1, wn = wid & 1;

    // fragment-linear LDS: frag f, lane l -> 16B at [f*512 + l*8] (ushort units)
    __shared__ __align__(16) ushort XH[2][MFRAG * 512];
    __shared__ __align__(16) ushort XL[2][MFRAG * 512];
    __shared__ __align__(16) ushort HH[2][NFRAG * 512];
    __shared__ __align__(16) ushort HL[2][NFRAG * 512];
    __shared__ float colsum[2][COLS];

    v4f acc[2][5];
    #pragma unroll
    for (int a = 0; a < 2; ++a)
        #pragma unroll
        for (int b = 0; b < 5; ++b) acc[a][b] = (v4f){0.f, 0.f, 0.f, 0.f};

    // stage X tile (64 rows x KT), f32 -> exact hi/lo bf16, fragment-linear
    auto stageX = [&](int buf, int kt) {
        #pragma unroll
        for (int s2 = 0; s2 < 2; ++s2) {
            int g = t + 256 * s2;           // 0..511
            int p = g >> 3;                 // padded row 0..63
            int k0 = (g & 7) << 2;          // 0,4,...,28
            float4 v = make_float4(0.f, 0.f, 0.f, 0.f);
            int r = p & 31;
            if (r < RES)
                v = *(const float4*)&x[(((bp << 1) + (p >> 5)) * RES + r) * D + kt + k0];
            ushort4 hu, lu;
            {
                ushort h; float rr;
                h = bf_hi(v.x); rr = v.x - us2f(h); hu.x = h; lu.x = bf_hi(rr);
                h = bf_hi(v.y); rr = v.y - us2f(h); hu.y = h; lu.y = bf_hi(rr);
                h = bf_hi(v.z); rr = v.z - us2f(h); hu.z = h; lu.z = bf_hi(rr);
                h = bf_hi(v.w); rr = v.w - us2f(h); hu.w = h; lu.w = bf_hi(rr);
            }
            int m = p >> 4, i = p & 15, q = k0 >> 3, off = (k0 & 7);
            int base = m * 512 + (q * 16 + i) * 8 + off;
            *(ushort4*)&XH[buf][base] = hu;
            *(ushort4*)&XL[buf][base] = lu;
        }
    };

    // stage H frags: global_load_lds 16B, linear LDS dest, pre-swizzled source
    auto stageH = [&](int buf, int kt) {
        #pragma unroll
        for (int j = 0; j < 5; ++j) {
            int cid = wid * 5 + j;                       // 0..19
            int n = (cid < 10) ? cid : cid - 10;
            const ushort* src = (cid < 10) ? Hth : Htl;
            ushort* dst = (cid < 10) ? &HH[buf][n * 512] : &HL[buf][n * 512];
            int row = cg * COLS + n * 16 + (lane & 15);
            const ushort* gp = &src[row * D + kt + ((lane >> 4) << 3)];
            __builtin_amdgcn_global_load_lds(
                (const __attribute__((address_space(1))) void*)gp,
                (__attribute__((address_space(3))) void*)dst, 16, 0, 0);
        }
    };

    auto compute = [&](int buf) {
        v8bf ah[2], al[2];
        #pragma unroll
        for (int mf = 0; mf < 2; ++mf) {
            int f = wm * 2 + mf;
            ah[mf] = *(const v8bf*)&XH[buf][f * 512 + lane * 8];
            al[mf] = *(const v8bf*)&XL[buf][f * 512 + lane * 8];
        }
        #pragma unroll
        for (int nf = 0; nf < 5; ++nf) {
            int f = wn * 5 + nf;
            v8bf bh = *(const v8bf*)&HH[buf][f * 512 + lane * 8];
            v8bf bl = *(const v8bf*)&HL[buf][f * 512 + lane * 8];
            #pragma unroll
            for (int mf = 0; mf < 2; ++mf) {
                acc[mf][nf] = __builtin_amdgcn_mfma_f32_16x16x32_bf16(ah[mf], bh, acc[mf][nf], 0, 0, 0);
                acc[mf][nf] = __builtin_amdgcn_mfma_f32_16x16x32_bf16(ah[mf], bl, acc[mf][nf], 0, 0, 0);
                acc[mf][nf] = __builtin_amdgcn_mfma_f32_16x16x32_bf16(al[mf], bh, acc[mf][nf], 0, 0, 0);
                acc[mf][nf] = __builtin_amdgcn_mfma_f32_16x16x32_bf16(al[mf], bl, acc[mf][nf], 0, 0, 0);
            }
        }
    };

    stageX(0, 0);
    stageH(0, 0);
    __syncthreads();
    for (int step = 0; step < NKT; ++step) {
        int cur = step & 1;
        if (step + 1 < NKT) {
            stageH(cur ^ 1, (step + 1) * KT);
            stageX(cur ^ 1, (step + 1) * KT);
        }
        compute(cur);
        __syncthreads();
    }

    // z^2 column sums; C-frag: col = lane&15, row = 4*(lane>>4)+j
    #pragma unroll
    for (int nf = 0; nf < 5; ++nf) {
        float part = 0.f;
        #pragma unroll
        for (int mf = 0; mf < 2; ++mf)
            #pragma unroll
            for (int j = 0; j < 4; ++j) part += acc[mf][nf][j] * acc[mf][nf][j];
        part += __shfl_xor(part, 16);
        part += __shfl_xor(part, 32);
        if ((lane >> 4) == 0) colsum[wm][wn * 80 + nf * 16 + lane] = part;
    }
    __syncthreads();
    if (t < 16) {
        int b = t >> 3, c = t & 7;
        float s = 0.f;
        #pragma unroll
        for (int i = 0; i < NSUP; ++i) s += colsum[b][c * 20 + i];
        S[((bp << 1) + b) * NC + cg * CPB + c] = s;
    }
}

// ---- Kernel 3: per-row min-max ----
__global__ __launch_bounds__(64) void k_minmax(const float* __restrict__ S,
                                               float* __restrict__ out) {
    const int b    = blockIdx.x;
    const int lane = threadIdx.x;
    float s  = S[b * NC + lane];
    float mn = s, mx = s;
    #pragma unroll
    for (int off = 32; off > 0; off >>= 1) {
        mn = fminf(mn, __shfl_xor(mn, off, 64));
        mx = fmaxf(mx, __shfl_xor(mx, off, 64));
    }
    out[b * NC + lane] = (s - mn) / (mx - mn);
}

extern "C" void kernel_launch(void* const* d_in, const int* in_sizes, int n_in,
                              void* d_out, int out_size, void* d_ws, size_t ws_size,
                              hipStream_t stream) {
    const float* x    = (const float*)d_in[0];
    const float* high = (const float*)d_in[1];
    float* out = (float*)d_out;

    ushort* Hth = (ushort*)d_ws;                       // 64*20*512 u16 = 1.31 MB
    ushort* Htl = Hth + NC * NSUP * D;                 // 1.31 MB
    float*  S   = (float*)(Htl + NC * NSUP * D);       // 128*64 f32 = 32 KB

    k_prep  <<<NC, 256, 0, stream>>>(high, Hth, Htl);
    k_main  <<<dim3(CPB, BB / 2), 256, 0, stream>>>(x, Hth, Htl, S);
    k_minmax<<<BB, 64, 0, stream>>>(S, out);
}

// Round 8
// 114.990 us; speedup vs baseline: 1.3144x; 1.3144x over previous
//
#include <hip/hip_runtime.h>

typedef __bf16 v8bf __attribute__((ext_vector_type(8)));
typedef float  v4f  __attribute__((ext_vector_type(4)));

#define D     512
#define NSUP  20
#define NC    64
#define RES   25
#define BB    128
#define LAM   (20.0f/512.0f)
#define KT    32
#define NKT   (D/KT)     // 16
#define CPB   8
#define COLS  160        // CPB*NSUP
#define NFRAG 10         // COLS/16
#define MFRAG 4          // 64 rows / 16

__device__ __forceinline__ ushort bf_hi(float v) {
    uint32_t b = __float_as_uint(v);
    return (ushort)((b + 0x7FFF + ((b >> 16) & 1)) >> 16);   // RNE
}
__device__ __forceinline__ float us2f(ushort u) {
    return __uint_as_float(((uint32_t)u) << 16);
}

// ---- Kernel 1:  B = G+lam I = L L^T;  C2 = G+2lam I = R R^T;
// ----            W = B^{-1} H (tri solves);  Htilde = R^T W  (hi/lo bf16 out)
// Identity: M = A + lam A^2 = B^{-1} C2 B^{-1}  (A = B^{-1})  =>
//           H^T M H = (R^T W)^T (R^T W).  No inverse, no Gauss-Jordan.
__global__ __launch_bounds__(256) void k_prep(const float* __restrict__ high,
                                              ushort* __restrict__ Hth,
                                              ushort* __restrict__ Htl) {
    const int cls = blockIdx.x;
    const int t   = threadIdx.x;
    __shared__ float Hc[NSUP * 516];
    __shared__ float Gs[NSUP * NSUP];
    __shared__ float Lb[NSUP * NSUP];    // chol of B (lower, col c at [i*20+c])
    __shared__ float Rc[NSUP * NSUP];    // chol of C2
    __shared__ float rLb[NSUP];          // 1/diag(L)

    // stage class rows (float4)
    for (int i = t; i < NSUP * (D / 4); i += 256) {
        int r = i >> 7, c4 = (i & 127) << 2;
        *(float4*)&Hc[r * 516 + c4] = *(const float4*)&high[(cls * NSUP + r) * D + c4];
    }
    __syncthreads();                                    // barrier 1

    // Gram — symmetric half only
    for (int e = t; e < NSUP * NSUP; e += 256) {
        int i = e / NSUP, j = e % NSUP;
        if (i <= j) {
            float s = 0.f;
            for (int k = 0; k < D; k += 4) {
                float4 a = *(float4*)&Hc[i * 516 + k];
                float4 b = *(float4*)&Hc[j * 516 + k];
                s += a.x * b.x + a.y * b.y + a.z * b.z + a.w * b.w;
            }
            Gs[i * NSUP + j] = s;
            Gs[j * NSUP + i] = s;
        }
    }
    __syncthreads();                                    // barrier 2

    // ---- dual in-register Cholesky on wave 0 (lanes 0-19: B, 32-51: C2) ----
    if (t < 64) {
        const int c  = t & 31;           // column within group
        const int gp = t >> 5;           // 0 = B (+lam), 1 = C2 (+2lam)
        const float dlam = gp ? 2.0f * LAM : LAM;
        float m[NSUP];
        if (c < NSUP) {
            #pragma unroll
            for (int i = 0; i < NSUP; ++i) m[i] = Gs[i * NSUP + c];
            #pragma unroll
            for (int i = 0; i < NSUP; ++i) if (i == c) m[i] += dlam;
        }
        #pragma unroll
        for (int k = 0; k < NSUP; ++k) {
            float piv = __shfl(m[k], k, 32);     // M[k][k] from lane k
            float sq  = sqrtf(piv);
            float rsq = 1.0f / sq;
            float lck = m[k] * rsq;              // L[c][k] via symmetry (c>k)
            if (c == k) {
                m[k] = sq;
                #pragma unroll
                for (int i = k + 1; i < NSUP; ++i) m[i] *= rsq;
            }
            #pragma unroll
            for (int i = k + 1; i < NSUP; ++i) {
                float lik = __shfl(m[i], k, 32); // L[i][k] (post-scale)
                if (c > k) m[i] -= lik * lck;    // keeps trailing block symmetric
            }
        }
        if (c < NSUP) {
            float* Lout = gp ? Rc : Lb;
            #pragma unroll
            for (int i = 0; i < NSUP; ++i) {
                if (i > c) Lout[i * NSUP + c] = m[i];
                else if (i == c) {
                    Lout[i * NSUP + c] = m[i];
                    if (!gp) rLb[c] = 1.0f / m[i];
                }
            }
        }
    }
    __syncthreads();                                    // barrier 3

    // ---- panel solves: per column  w = B^{-1} h,  ht = R^T w  -------------
    #pragma unroll
    for (int half = 0; half < 2; ++half) {
        const int col = t + half * 256;
        float h[NSUP];
        #pragma unroll
        for (int m2 = 0; m2 < NSUP; ++m2) h[m2] = Hc[m2 * 516 + col];
        // forward: L z = h   (L reads are wave-uniform broadcasts)
        #pragma unroll
        for (int i = 0; i < NSUP; ++i) {
            float s = h[i];
            #pragma unroll
            for (int m2 = 0; m2 < i; ++m2) s -= Lb[i * NSUP + m2] * h[m2];
            h[i] = s * rLb[i];
        }
        // backward: L^T w = z
        #pragma unroll
        for (int i = NSUP - 1; i >= 0; --i) {
            float s = h[i];
            #pragma unroll
            for (int m2 = i + 1; m2 < NSUP; ++m2) s -= Lb[m2 * NSUP + i] * h[m2];
            h[i] = s * rLb[i];
        }
        // ht[i] = sum_{m>=i} R[m][i] * w[m];  exact hi/lo bf16 split
        #pragma unroll
        for (int i = 0; i < NSUP; ++i) {
            float s = 0.f;
            #pragma unroll
            for (int m2 = i; m2 < NSUP; ++m2) s += Rc[m2 * NSUP + i] * h[m2];
            ushort hh = bf_hi(s);
            float  rr = s - us2f(hh);
            Hth[(cls * NSUP + i) * D + col] = hh;
            Htl[(cls * NSUP + i) * D + col] = bf_hi(rr);
        }
    }
}

// ---- Kernel 2: Z = X @ Htilde^T via 4-pass hi/lo bf16 MFMA; S = sum z^2 ----
// grid (8 class-groups, 64 batch-pairs), 256 threads = 4 waves (2M x 2N)
__global__ __launch_bounds__(256, 2) void k_main(const float* __restrict__ x,
                                                 const ushort* __restrict__ Hth,
                                                 const ushort* __restrict__ Htl,
                                                 float* __restrict__ S) {
    const int cg = blockIdx.x, bp = blockIdx.y;
    const int t = threadIdx.x, lane = t & 63, wid = t >> 6;
    const int wm = wid >> 1, wn = wid & 1;

    // fragment-linear LDS: frag f, lane l -> 16B at [f*512 + l*8] (ushort units)
    __shared__ __align__(16) ushort XH[2][MFRAG * 512];
    __shared__ __align__(16) ushort XL[2][MFRAG * 512];
    __shared__ __align__(16) ushort HH[2][NFRAG * 512];
    __shared__ __align__(16) ushort HL[2][NFRAG * 512];
    __shared__ float colsum[2][COLS];

    v4f acc[2][5];
    #pragma unroll
    for (int a = 0; a < 2; ++a)
        #pragma unroll
        for (int b = 0; b < 5; ++b) acc[a][b] = (v4f){0.f, 0.f, 0.f, 0.f};

    // stage X tile (64 rows x KT), f32 -> exact hi/lo bf16, fragment-linear
    auto stageX = [&](int buf, int kt) {
        #pragma unroll
        for (int s2 = 0; s2 < 2; ++s2) {
            int g = t + 256 * s2;           // 0..511
            int p = g >> 3;                 // padded row 0..63
            int k0 = (g & 7) << 2;          // 0,4,...,28
            float4 v = make_float4(0.f, 0.f, 0.f, 0.f);
            int r = p & 31;
            if (r < RES)
                v = *(const float4*)&x[(((bp << 1) + (p >> 5)) * RES + r) * D + kt + k0];
            ushort4 hu, lu;
            {
                ushort h; float rr;
                h = bf_hi(v.x); rr = v.x - us2f(h); hu.x = h; lu.x = bf_hi(rr);
                h = bf_hi(v.y); rr = v.y - us2f(h); hu.y = h; lu.y = bf_hi(rr);
                h = bf_hi(v.z); rr = v.z - us2f(h); hu.z = h; lu.z = bf_hi(rr);
                h = bf_hi(v.w); rr = v.w - us2f(h); hu.w = h; lu.w = bf_hi(rr);
            }
            int m = p >> 4, i = p & 15, q = k0 >> 3, off = (k0 & 7);
            int base = m * 512 + (q * 16 + i) * 8 + off;
            *(ushort4*)&XH[buf][base] = hu;
            *(ushort4*)&XL[buf][base] = lu;
        }
    };

    // stage H frags: global_load_lds 16B, linear LDS dest, pre-swizzled source
    auto stageH = [&](int buf, int kt) {
        #pragma unroll
        for (int j = 0; j < 5; ++j) {
            int cid = wid * 5 + j;                       // 0..19
            int n = (cid < 10) ? cid : cid - 10;
            const ushort* src = (cid < 10) ? Hth : Htl;
            ushort* dst = (cid < 10) ? &HH[buf][n * 512] : &HL[buf][n * 512];
            int row = cg * COLS + n * 16 + (lane & 15);
            const ushort* gp = &src[row * D + kt + ((lane >> 4) << 3)];
            __builtin_amdgcn_global_load_lds(
                (const __attribute__((address_space(1))) void*)gp,
                (__attribute__((address_space(3))) void*)dst, 16, 0, 0);
        }
    };

    auto compute = [&](int buf) {
        v8bf ah[2], al[2];
        #pragma unroll
        for (int mf = 0; mf < 2; ++mf) {
            int f = wm * 2 + mf;
            ah[mf] = *(const v8bf*)&XH[buf][f * 512 + lane * 8];
            al[mf] = *(const v8bf*)&XL[buf][f * 512 + lane * 8];
        }
        #pragma unroll
        for (int nf = 0; nf < 5; ++nf) {
            int f = wn * 5 + nf;
            v8bf bh = *(const v8bf*)&HH[buf][f * 512 + lane * 8];
            v8bf bl = *(const v8bf*)&HL[buf][f * 512 + lane * 8];
            #pragma unroll
            for (int mf = 0; mf < 2; ++mf) {
                acc[mf][nf] = __builtin_amdgcn_mfma_f32_16x16x32_bf16(ah[mf], bh, acc[mf][nf], 0, 0, 0);
                acc[mf][nf] = __builtin_amdgcn_mfma_f32_16x16x32_bf16(ah[mf], bl, acc[mf][nf], 0, 0, 0);
                acc[mf][nf] = __builtin_amdgcn_mfma_f32_16x16x32_bf16(al[mf], bh, acc[mf][nf], 0, 0, 0);
                acc[mf][nf] = __builtin_amdgcn_mfma_f32_16x16x32_bf16(al[mf], bl, acc[mf][nf], 0, 0, 0);
            }
        }
    };

    stageX(0, 0);
    stageH(0, 0);
    __syncthreads();
    for (int step = 0; step < NKT; ++step) {
        int cur = step & 1;
        if (step + 1 < NKT) {
            stageH(cur ^ 1, (step + 1) * KT);
            stageX(cur ^ 1, (step + 1) * KT);
        }
        compute(cur);
        __syncthreads();
    }

    // z^2 column sums; C-frag: col = lane&15, row = 4*(lane>>4)+j
    #pragma unroll
    for (int nf = 0; nf < 5; ++nf) {
        float part = 0.f;
        #pragma unroll
        for (int mf = 0; mf < 2; ++mf)
            #pragma unroll
            for (int j = 0; j < 4; ++j) part += acc[mf][nf][j] * acc[mf][nf][j];
        part += __shfl_xor(part, 16);
        part += __shfl_xor(part, 32);
        if ((lane >> 4) == 0) colsum[wm][wn * 80 + nf * 16 + lane] = part;
    }
    __syncthreads();
    if (t < 16) {
        int b = t >> 3, c = t & 7;
        float s = 0.f;
        #pragma unroll
        for (int i = 0; i < NSUP; ++i) s += colsum[b][c * 20 + i];
        S[((bp << 1) + b) * NC + cg * CPB + c] = s;
    }
}

// ---- Kernel 3: per-row min-max ----
__global__ __launch_bounds__(64) void k_minmax(const float* __restrict__ S,
                                               float* __restrict__ out) {
    const int b    = blockIdx.x;
    const int lane = threadIdx.x;
    float s  = S[b * NC + lane];
    float mn = s, mx = s;
    #pragma unroll
    for (int off = 32; off > 0; off >>= 1) {
        mn = fminf(mn, __shfl_xor(mn, off, 64));
        mx = fmaxf(mx, __shfl_xor(mx, off, 64));
    }
    out[b * NC + lane] = (s - mn) / (mx - mn);
}

extern "C" void kernel_launch(void* const* d_in, const int* in_sizes, int n_in,
                              void* d_out, int out_size, void* d_ws, size_t ws_size,
                              hipStream_t stream) {
    const float* x    = (const float*)d_in[0];
    const float* high = (const float*)d_in[1];
    float* out = (float*)d_out;

    ushort* Hth = (ushort*)d_ws;                       // 64*20*512 u16 = 1.31 MB
    ushort* Htl = Hth + NC * NSUP * D;                 // 1.31 MB
    float*  S   = (float*)(Htl + NC * NSUP * D);       // 128*64 f32 = 32 KB

    k_prep  <<<NC, 256, 0, stream>>>(high, Hth, Htl);
    k_main  <<<dim3(CPB, BB / 2), 256, 0, stream>>>(x, Hth, Htl, S);
    k_minmax<<<BB, 64, 0, stream>>>(S, out);
}

// Round 9
// 110.902 us; speedup vs baseline: 1.3628x; 1.0369x over previous
//
#include <hip/hip_runtime.h>

typedef __bf16 v8bf __attribute__((ext_vector_type(8)));
typedef float  v4f  __attribute__((ext_vector_type(4)));

#define D     512
#define NSUP  20
#define NC    64
#define RES   25
#define BB    128
#define LAM   (20.0f/512.0f)
#define KT    32
#define NKT   (D/KT)     // 16
#define CPB   8
#define COLS  160        // CPB*NSUP
#define NFRAG 10         // COLS/16
#define MFRAG 4          // 64 rows / 16
#define LRSZ  820        // per-class: Lb[400] | Rc[400] | rLb[20]

__device__ __forceinline__ ushort bf_hi(float v) {
    uint32_t b = __float_as_uint(v);
    return (ushort)((b + 0x7FFF + ((b >> 16) & 1)) >> 16);   // RNE
}
__device__ __forceinline__ float us2f(ushort u) {
    return __uint_as_float(((uint32_t)u) << 16);
}

// ---- Kernel 1a: Gram + dual in-register Cholesky ---------------------------
//  B = G+lam I = L L^T ; C2 = G+2lam I = R R^T ; writes L,R,1/diag(L) to ws.
__global__ __launch_bounds__(256) void k_prep1(const float* __restrict__ high,
                                               float* __restrict__ LR) {
    const int cls = blockIdx.x;
    const int t   = threadIdx.x;
    __shared__ float Hc[NSUP * 516];
    __shared__ float Gs[NSUP * NSUP];

    for (int i = t; i < NSUP * (D / 4); i += 256) {
        int r = i >> 7, c4 = (i & 127) << 2;
        *(float4*)&Hc[r * 516 + c4] = *(const float4*)&high[(cls * NSUP + r) * D + c4];
    }
    __syncthreads();

    for (int e = t; e < NSUP * NSUP; e += 256) {
        int i = e / NSUP, j = e % NSUP;
        if (i <= j) {
            float s = 0.f;
            for (int k = 0; k < D; k += 4) {
                float4 a = *(float4*)&Hc[i * 516 + k];
                float4 b = *(float4*)&Hc[j * 516 + k];
                s += a.x * b.x + a.y * b.y + a.z * b.z + a.w * b.w;
            }
            Gs[i * NSUP + j] = s;
            Gs[j * NSUP + i] = s;
        }
    }
    __syncthreads();

    // dual in-register Cholesky on wave 0 (lanes 0-19: B, 32-51: C2)
    if (t < 64) {
        const int c  = t & 31;
        const int gp = t >> 5;
        const float dlam = gp ? 2.0f * LAM : LAM;
        float m[NSUP];
        if (c < NSUP) {
            #pragma unroll
            for (int i = 0; i < NSUP; ++i) m[i] = Gs[i * NSUP + c];
            #pragma unroll
            for (int i = 0; i < NSUP; ++i) if (i == c) m[i] += dlam;
        }
        #pragma unroll
        for (int k = 0; k < NSUP; ++k) {
            float piv = __shfl(m[k], k, 32);     // M[k][k] from lane k
            float sq  = sqrtf(piv);
            float rsq = 1.0f / sq;
            float lck = m[k] * rsq;              // L[c][k] via symmetry (c>k)
            if (c == k) {
                m[k] = sq;
                #pragma unroll
                for (int i = k + 1; i < NSUP; ++i) m[i] *= rsq;
            }
            #pragma unroll
            for (int i = k + 1; i < NSUP; ++i) {
                float lik = __shfl(m[i], k, 32); // L[i][k] (post-scale)
                if (c > k) m[i] -= lik * lck;
            }
        }
        if (c < NSUP) {
            float* base = LR + cls * LRSZ + (gp ? 400 : 0);
            #pragma unroll
            for (int i = 0; i < NSUP; ++i) if (i >= c) base[i * NSUP + c] = m[i];
            if (!gp) LR[cls * LRSZ + 800 + c] = 1.0f / m[c];
        }
    }
}

// ---- Kernel 1b: panel solves, 2 blocks/class x 256 cols --------------------
//  w = B^{-1} h (fwd+bwd); Htilde = R^T w; exact hi/lo bf16 split out.
__global__ __launch_bounds__(256) void k_prep2(const float* __restrict__ high,
                                               const float* __restrict__ LR,
                                               ushort* __restrict__ Hth,
                                               ushort* __restrict__ Htl) {
    const int cls = blockIdx.x;
    const int col = blockIdx.y * 256 + threadIdx.x;
    const int t   = threadIdx.x;
    __shared__ float Ls[400], Rs[400], rL[NSUP];

    for (int i = t; i < 400; i += 256) Ls[i] = LR[cls * LRSZ + i];
    for (int i = t; i < 400; i += 256) Rs[i] = LR[cls * LRSZ + 400 + i];
    if (t < NSUP) rL[t] = LR[cls * LRSZ + 800 + t];
    __syncthreads();

    float h[NSUP];
    #pragma unroll
    for (int m = 0; m < NSUP; ++m) h[m] = high[(cls * NSUP + m) * D + col];
    // forward: L z = h
    #pragma unroll
    for (int i = 0; i < NSUP; ++i) {
        float s = h[i];
        #pragma unroll
        for (int m = 0; m < i; ++m) s -= Ls[i * NSUP + m] * h[m];
        h[i] = s * rL[i];
    }
    // backward: L^T w = z
    #pragma unroll
    for (int i = NSUP - 1; i >= 0; --i) {
        float s = h[i];
        #pragma unroll
        for (int m = i + 1; m < NSUP; ++m) s -= Ls[m * NSUP + i] * h[m];
        h[i] = s * rL[i];
    }
    // ht[i] = sum_{m>=i} R[m][i] * w[m]
    #pragma unroll
    for (int i = 0; i < NSUP; ++i) {
        float s = 0.f;
        #pragma unroll
        for (int m = i; m < NSUP; ++m) s += Rs[m * NSUP + i] * h[m];
        ushort hh = bf_hi(s);
        float  rr = s - us2f(hh);
        Hth[(cls * NSUP + i) * D + col] = hh;
        Htl[(cls * NSUP + i) * D + col] = bf_hi(rr);
    }
}

// ---- Kernel 2: Z = X @ Htilde^T via 3-pass hi/lo bf16 MFMA; S = sum z^2 ----
// grid (8 class-groups, 64 batch-pairs), 256 threads = 4 waves (2M x 2N)
__global__ __launch_bounds__(256, 2) void k_main(const float* __restrict__ x,
                                                 const ushort* __restrict__ Hth,
                                                 const ushort* __restrict__ Htl,
                                                 float* __restrict__ S) {
    const int cg = blockIdx.x, bp = blockIdx.y;
    const int t = threadIdx.x, lane = t & 63, wid = t >> 6;
    const int wm = wid >> 1, wn = wid & 1;

    // fragment-linear LDS: frag f, lane l -> 16B at [f*512 + l*8] (ushort units)
    __shared__ __align__(16) ushort XH[2][MFRAG * 512];
    __shared__ __align__(16) ushort XL[2][MFRAG * 512];
    __shared__ __align__(16) ushort HH[2][NFRAG * 512];
    __shared__ __align__(16) ushort HL[2][NFRAG * 512];
    __shared__ float colsum[2][COLS];

    v4f acc[2][5];
    #pragma unroll
    for (int a = 0; a < 2; ++a)
        #pragma unroll
        for (int b = 0; b < 5; ++b) acc[a][b] = (v4f){0.f, 0.f, 0.f, 0.f};

    auto stageX = [&](int buf, int kt) {
        #pragma unroll
        for (int s2 = 0; s2 < 2; ++s2) {
            int g = t + 256 * s2;           // 0..511
            int p = g >> 3;                 // padded row 0..63
            int k0 = (g & 7) << 2;          // 0,4,...,28
            float4 v = make_float4(0.f, 0.f, 0.f, 0.f);
            int r = p & 31;
            if (r < RES)
                v = *(const float4*)&x[(((bp << 1) + (p >> 5)) * RES + r) * D + kt + k0];
            ushort4 hu, lu;
            {
                ushort h; float rr;
                h = bf_hi(v.x); rr = v.x - us2f(h); hu.x = h; lu.x = bf_hi(rr);
                h = bf_hi(v.y); rr = v.y - us2f(h); hu.y = h; lu.y = bf_hi(rr);
                h = bf_hi(v.z); rr = v.z - us2f(h); hu.z = h; lu.z = bf_hi(rr);
                h = bf_hi(v.w); rr = v.w - us2f(h); hu.w = h; lu.w = bf_hi(rr);
            }
            int m = p >> 4, i = p & 15, q = k0 >> 3, off = (k0 & 7);
            int base = m * 512 + (q * 16 + i) * 8 + off;
            *(ushort4*)&XH[buf][base] = hu;
            *(ushort4*)&XL[buf][base] = lu;
        }
    };

    auto stageH = [&](int buf, int kt) {
        #pragma unroll
        for (int j = 0; j < 5; ++j) {
            int cid = wid * 5 + j;                       // 0..19
            int n = (cid < 10) ? cid : cid - 10;
            const ushort* src = (cid < 10) ? Hth : Htl;
            ushort* dst = (cid < 10) ? &HH[buf][n * 512] : &HL[buf][n * 512];
            int row = cg * COLS + n * 16 + (lane & 15);
            const ushort* gp = &src[row * D + kt + ((lane >> 4) << 3)];
            __builtin_amdgcn_global_load_lds(
                (const __attribute__((address_space(1))) void*)gp,
                (__attribute__((address_space(3))) void*)dst, 16, 0, 0);
        }
    };

    auto compute = [&](int buf) {
        v8bf ah[2], al[2];
        #pragma unroll
        for (int mf = 0; mf < 2; ++mf) {
            int f = wm * 2 + mf;
            ah[mf] = *(const v8bf*)&XH[buf][f * 512 + lane * 8];
            al[mf] = *(const v8bf*)&XL[buf][f * 512 + lane * 8];
        }
        #pragma unroll
        for (int nf = 0; nf < 5; ++nf) {
            int f = wn * 5 + nf;
            v8bf bh = *(const v8bf*)&HH[buf][f * 512 + lane * 8];
            v8bf bl = *(const v8bf*)&HL[buf][f * 512 + lane * 8];
            #pragma unroll
            for (int mf = 0; mf < 2; ++mf) {
                // 3-pass: drop al*bl (<= 2^-18 relative)
                acc[mf][nf] = __builtin_amdgcn_mfma_f32_16x16x32_bf16(ah[mf], bh, acc[mf][nf], 0, 0, 0);
                acc[mf][nf] = __builtin_amdgcn_mfma_f32_16x16x32_bf16(ah[mf], bl, acc[mf][nf], 0, 0, 0);
                acc[mf][nf] = __builtin_amdgcn_mfma_f32_16x16x32_bf16(al[mf], bh, acc[mf][nf], 0, 0, 0);
            }
        }
    };

    stageX(0, 0);
    stageH(0, 0);
    __syncthreads();
    for (int step = 0; step < NKT; ++step) {
        int cur = step & 1;
        if (step + 1 < NKT) {
            stageH(cur ^ 1, (step + 1) * KT);
            stageX(cur ^ 1, (step + 1) * KT);
        }
        compute(cur);
        __syncthreads();
    }

    // z^2 column sums; C-frag: col = lane&15, row = 4*(lane>>4)+j
    #pragma unroll
    for (int nf = 0; nf < 5; ++nf) {
        float part = 0.f;
        #pragma unroll
        for (int mf = 0; mf < 2; ++mf)
            #pragma unroll
            for (int j = 0; j < 4; ++j) part += acc[mf][nf][j] * acc[mf][nf][j];
        part += __shfl_xor(part, 16);
        part += __shfl_xor(part, 32);
        if ((lane >> 4) == 0) colsum[wm][wn * 80 + nf * 16 + lane] = part;
    }
    __syncthreads();
    if (t < 16) {
        int b = t >> 3, c = t & 7;
        float s = 0.f;
        #pragma unroll
        for (int i = 0; i < NSUP; ++i) s += colsum[b][c * 20 + i];
        S[((bp << 1) + b) * NC + cg * CPB + c] = s;
    }
}

// ---- Kernel 3: per-row min-max ----
__global__ __launch_bounds__(64) void k_minmax(const float* __restrict__ S,
                                               float* __restrict__ out) {
    const int b    = blockIdx.x;
    const int lane = threadIdx.x;
    float s  = S[b * NC + lane];
    float mn = s, mx = s;
    #pragma unroll
    for (int off = 32; off > 0; off >>= 1) {
        mn = fminf(mn, __shfl_xor(mn, off, 64));
        mx = fmaxf(mx, __shfl_xor(mx, off, 64));
    }
    out[b * NC + lane] = (s - mn) / (mx - mn);
}

extern "C" void kernel_launch(void* const* d_in, const int* in_sizes, int n_in,
                              void* d_out, int out_size, void* d_ws, size_t ws_size,
                              hipStream_t stream) {
    const float* x    = (const float*)d_in[0];
    const float* high = (const float*)d_in[1];
    float* out = (float*)d_out;

    ushort* Hth = (ushort*)d_ws;                       // 64*20*512 u16 = 1.31 MB
    ushort* Htl = Hth + NC * NSUP * D;                 // 1.31 MB
    float*  S   = (float*)(Htl + NC * NSUP * D);       // 32 KB
    float*  LR  = S + BB * NC;                         // 64*820 f32 = 210 KB

    k_prep1 <<<NC, 256, 0, stream>>>(high, LR);
    k_prep2 <<<dim3(NC, 2), 256, 0, stream>>>(high, LR, Hth, Htl);
    k_main  <<<dim3(CPB, BB / 2), 256, 0, stream>>>(x, Hth, Htl, S);
    k_minmax<<<BB, 64, 0, stream>>>(S, out);
}